// Round 5
// baseline (223.875 us; speedup 1.0000x reference)
//
#include <hip/hip_runtime.h>

#define NN 50000
#define NE 800000
#define KIN 256
#define DOUT 128
#define NEG_SLOPE 0.2f
#define ALPHA 0.5f
#define ELL_CAP 48

typedef __attribute__((ext_vector_type(8))) short bf16x8;
typedef __attribute__((ext_vector_type(4))) float f32x4;

__device__ __forceinline__ unsigned short f2b(float v) {
  unsigned int u = __float_as_uint(v);
  return (unsigned short)((u + 0x7fffu + ((u >> 16) & 1u)) >> 16);
}
__device__ __forceinline__ float b2f(unsigned short h) {
  return __uint_as_float(((unsigned int)h) << 16);
}
__device__ __forceinline__ unsigned short f2h(float v) {
  _Float16 h = (_Float16)v;
  return __builtin_bit_cast(unsigned short, h);
}
__device__ __forceinline__ float h2f(unsigned short u) {
  return (float)__builtin_bit_cast(_Float16, u);
}

// ---- split fc_w into bf16 hi/lo, fragment-friendly layout
// idx = ((kt*128 + c)*4 + g)*8 + j  for k = kt*32 + g*8 + j
__global__ void prep_b(const float* __restrict__ fc_w, unsigned short* __restrict__ b_hi,
                       unsigned short* __restrict__ b_lo) {
  int t = blockIdx.x * 256 + threadIdx.x;
  if (t >= KIN * DOUT) return;
  int k = t >> 7, c = t & 127;
  float v = fc_w[t];
  unsigned short h = f2b(v);
  unsigned short l = f2b(v - b2f(h));
  int kt = k >> 5, kl = k & 31;
  int g = kl >> 3, j = kl & 7;
  int idx = ((kt * 128 + c) * 4 + g) * 8 + j;
  b_hi[idx] = h;
  b_lo[idx] = l;
}

// ---- ft = feat @ fc_w via split-bf16 MFMA, LDS-free; fused el/er epilogue
__global__ __launch_bounds__(256) void gemm_ft(
    const float* __restrict__ feat, const unsigned short* __restrict__ b_hi,
    const unsigned short* __restrict__ b_lo, const float* __restrict__ attn_l,
    const float* __restrict__ attn_r, unsigned short* __restrict__ ft16,
    float* __restrict__ el, float* __restrict__ er) {
  const int tid = threadIdx.x;
  const int lane = tid & 63;
  const int wv = tid >> 6;
  const int cl = lane & 15;
  const int g = lane >> 4;
  const int row = blockIdx.x * 64 + wv * 16 + cl;
  const size_t arow = (size_t)min(row, NN - 1) * KIN;
  const int boff0 = cl * 32 + g * 8;

  f32x4 acc[8];
#pragma unroll
  for (int ct = 0; ct < 8; ++ct) acc[ct] = (f32x4){0.f, 0.f, 0.f, 0.f};

#pragma unroll
  for (int kt = 0; kt < 8; ++kt) {
    const float* ap = feat + arow + kt * 32 + g * 8;
    float4 a0 = *(const float4*)ap;
    float4 a1 = *(const float4*)(ap + 4);
    bf16x8 ah, alo;
    {
      float f[8] = {a0.x, a0.y, a0.z, a0.w, a1.x, a1.y, a1.z, a1.w};
#pragma unroll
      for (int j = 0; j < 8; ++j) {
        unsigned short h = f2b(f[j]);
        ah[j] = (short)h;
        alo[j] = (short)f2b(f[j] - b2f(h));
      }
    }
    const unsigned short* bh = b_hi + kt * 4096 + boff0;
    const unsigned short* bl = b_lo + kt * 4096 + boff0;
#pragma unroll
    for (int ct = 0; ct < 8; ++ct) {
      bf16x8 bhv = *(const bf16x8*)(bh + ct * 512);
      bf16x8 blv = *(const bf16x8*)(bl + ct * 512);
      acc[ct] = __builtin_amdgcn_mfma_f32_16x16x32_bf16(ah, bhv, acc[ct], 0, 0, 0);
      acc[ct] = __builtin_amdgcn_mfma_f32_16x16x32_bf16(alo, bhv, acc[ct], 0, 0, 0);
      acc[ct] = __builtin_amdgcn_mfma_f32_16x16x32_bf16(ah, blv, acc[ct], 0, 0, 0);
    }
  }

  float pl[4] = {0, 0, 0, 0}, pr[4] = {0, 0, 0, 0};
  const int r0 = blockIdx.x * 64 + wv * 16 + g * 4;
#pragma unroll
  for (int ct = 0; ct < 8; ++ct) {
    int col = ct * 16 + cl;
    float av = attn_l[col];
    float bv = attn_r[col];
#pragma unroll
    for (int q = 0; q < 4; ++q) {
      float v = acc[ct][q];
      int r = r0 + q;
      if (r < NN) ft16[(size_t)r * DOUT + col] = f2b(v);
      pl[q] = fmaf(v, av, pl[q]);
      pr[q] = fmaf(v, bv, pr[q]);
    }
  }
#pragma unroll
  for (int q = 0; q < 4; ++q) {
    float a = pl[q], b = pr[q];
#pragma unroll
    for (int d = 1; d < 16; d <<= 1) {
      a += __shfl_xor(a, d);
      b += __shfl_xor(b, d);
    }
    if (cl == 0) {
      int r = r0 + q;
      if (r < NN) { el[r] = a; er[r] = b; }
    }
  }
}

// ---- single edge pass: 4 edges/thread; 1 atomic + one 4B packed store/edge
//      entry = (src << 16) | fp16(w)
__global__ void edge_ell(const int* __restrict__ src, const int* __restrict__ dst,
                         const float* __restrict__ w, int* __restrict__ deg,
                         unsigned int* __restrict__ ell) {
  int t = blockIdx.x * 256 + threadIdx.x;
  int e0 = t * 4;
  if (e0 >= NE) return;
  int4 s4 = *(const int4*)(src + e0);
  int4 d4 = *(const int4*)(dst + e0);
  float4 w4 = *(const float4*)(w + e0);
  int p0 = atomicAdd(&deg[d4.x], 1);
  int p1 = atomicAdd(&deg[d4.y], 1);
  int p2 = atomicAdd(&deg[d4.z], 1);
  int p3 = atomicAdd(&deg[d4.w], 1);
  if (p0 < ELL_CAP) ell[d4.x * ELL_CAP + p0] = ((unsigned)s4.x << 16) | f2h(w4.x);
  if (p1 < ELL_CAP) ell[d4.y * ELL_CAP + p1] = ((unsigned)s4.y << 16) | f2h(w4.y);
  if (p2 < ELL_CAP) ell[d4.z * ELL_CAP + p2] = ((unsigned)s4.z << 16) | f2h(w4.z);
  if (p3 < ELL_CAP) ell[d4.w * ELL_CAP + p3] = ((unsigned)s4.w << 16) | f2h(w4.w);
}

// ---- aggregation: one wave per dst node; softmax in-register,
//      4 edges/step with 16 lanes x 16B gathers per row
__global__ __launch_bounds__(256) void aggregate(
    const unsigned short* __restrict__ ft16, const unsigned int* __restrict__ ell,
    const int* __restrict__ deg, const float* __restrict__ el,
    const float* __restrict__ er, const float* __restrict__ bias,
    float* __restrict__ out) {
  const int lane = threadIdx.x & 63;
  const int wv = threadIdx.x >> 6;
  const int n = blockIdx.x * 4 + wv;
  if (n >= NN) return;
  const int dg = min(deg[n], ELL_CAP);
  const float ern = er[n];

  float z = 0.f, zw = 0.f;
  int so = 0;
  if (lane < dg) {
    unsigned int ent = ell[n * ELL_CAP + lane];
    int s = (int)(ent >> 16);
    so = s * DOUT;
    float x = el[s] + ern;
    x = (x > 0.f) ? x : NEG_SLOPE * x;
    z = __expf(x);                         // max-free: |logit| bounded ~12
    zw = __expf(h2f((unsigned short)(ent & 0xffffu)));
  }
  float se = z, sw = zw;
#pragma unroll
  for (int d = 1; d < 64; d <<= 1) {
    se += __shfl_xor(se, d);
    sw += __shfl_xor(sw, d);
  }
  const float coef = z * ((1.f - ALPHA) / se) + zw * (ALPHA / sw);  // 0 for idle lanes

  float acc[8] = {0.f, 0.f, 0.f, 0.f, 0.f, 0.f, 0.f, 0.f};
  const unsigned short* ftp = ft16 + (lane & 15) * 8;
  for (int jb = 0; jb < dg; jb += 4) {
    int j = jb + (lane >> 4);
    float cj = __shfl(coef, j);   // coef==0 beyond dg -> harmless row-0 read
    int soj = __shfl(so, j);
    bf16x8 row = *(const bf16x8*)(ftp + soj);
#pragma unroll
    for (int c = 0; c < 8; ++c)
      acc[c] = fmaf(cj, b2f((unsigned short)row[c]), acc[c]);
  }
#pragma unroll
  for (int c = 0; c < 8; ++c) {
    acc[c] += __shfl_xor(acc[c], 16);
    acc[c] += __shfl_xor(acc[c], 32);
  }
  if (lane < 16) {
    const float4 b0 = *(const float4*)(bias + lane * 8);
    const float4 b1 = *(const float4*)(bias + lane * 8 + 4);
    float4 o0, o1;
    o0.x = acc[0] + b0.x; o0.y = acc[1] + b0.y; o0.z = acc[2] + b0.z; o0.w = acc[3] + b0.w;
    o1.x = acc[4] + b1.x; o1.y = acc[5] + b1.y; o1.z = acc[6] + b1.z; o1.w = acc[7] + b1.w;
    float* op = out + (size_t)n * DOUT + lane * 8;
    *(float4*)op = o0;
    *(float4*)(op + 4) = o1;
  }
}

extern "C" void kernel_launch(void* const* d_in, const int* in_sizes, int n_in,
                              void* d_out, int out_size, void* d_ws, size_t ws_size,
                              hipStream_t stream) {
  const float* feat = (const float*)d_in[0];
  const float* w = (const float*)d_in[1];
  const float* fc_w = (const float*)d_in[2];
  const float* attn_l = (const float*)d_in[3];
  const float* attn_r = (const float*)d_in[4];
  const float* bias = (const float*)d_in[5];
  const int* src = (const int*)d_in[6];
  const int* dst = (const int*)d_in[7];
  float* out = (float*)d_out;

  char* ws = (char*)d_ws;
  size_t o = 0;
  auto take = [&](size_t bytes) {
    char* p = ws + o;
    o = (o + bytes + 255) & ~(size_t)255;
    return p;
  };
  unsigned short* ft16 = (unsigned short*)take((size_t)NN * DOUT * 2);
  float* el = (float*)take((size_t)NN * 4);
  float* er = (float*)take((size_t)NN * 4);
  unsigned short* b_hi = (unsigned short*)take((size_t)KIN * DOUT * 2);
  unsigned short* b_lo = (unsigned short*)take((size_t)KIN * DOUT * 2);
  int* deg = (int*)take((size_t)NN * 4);
  unsigned int* ell = (unsigned int*)take((size_t)NN * ELL_CAP * 4);

  hipMemsetAsync(deg, 0, (size_t)NN * 4, stream);
  prep_b<<<(KIN * DOUT + 255) / 256, 256, 0, stream>>>(fc_w, b_hi, b_lo);
  edge_ell<<<(NE / 4 + 255) / 256, 256, 0, stream>>>(src, dst, w, deg, ell);
  gemm_ft<<<(NN + 63) / 64, 256, 0, stream>>>(feat, b_hi, b_lo, attn_l, attn_r, ft16, el, er);
  aggregate<<<(NN + 3) / 4, 256, 0, stream>>>(ft16, ell, deg, el, er, bias, out);
}

// Round 6
// 220.807 us; speedup vs baseline: 1.0139x; 1.0139x over previous
//
#include <hip/hip_runtime.h>

#define NN 50000
#define NE 800000
#define KIN 256
#define DOUT 128
#define NEG_SLOPE 0.2f
#define ALPHA 0.5f

#define GB 6                      // 64 dsts per group
#define GSZ 64
#define NG ((NN + GSZ - 1) / GSZ) // 782
#define EPB 8192
#define NB ((NE + EPB - 1) / EPB) // 98
#define HTOT (NG * NB)            // 76,636
#define GCAP 1536                 // mean 1024, sigma 32 -> 16 sigma headroom

typedef __attribute__((ext_vector_type(8))) short bf16x8;
typedef __attribute__((ext_vector_type(4))) float f32x4;

__device__ __forceinline__ unsigned short f2b(float v) {
  unsigned int u = __float_as_uint(v);
  return (unsigned short)((u + 0x7fffu + ((u >> 16) & 1u)) >> 16);
}
__device__ __forceinline__ float b2f(unsigned short h) {
  return __uint_as_float(((unsigned int)h) << 16);
}
__device__ __forceinline__ unsigned short f2h(float v) {
  _Float16 h = (_Float16)v;
  return __builtin_bit_cast(unsigned short, h);
}
__device__ __forceinline__ float h2f(unsigned short u) {
  return (float)__builtin_bit_cast(_Float16, u);
}

// ---- split fc_w into bf16 hi/lo, fragment-friendly layout
__global__ void prep_b(const float* __restrict__ fc_w, unsigned short* __restrict__ b_hi,
                       unsigned short* __restrict__ b_lo) {
  int t = blockIdx.x * 256 + threadIdx.x;
  if (t >= KIN * DOUT) return;
  int k = t >> 7, c = t & 127;
  float v = fc_w[t];
  unsigned short h = f2b(v);
  unsigned short l = f2b(v - b2f(h));
  int kt = k >> 5, kl = k & 31;
  int g = kl >> 3, j = kl & 7;
  int idx = ((kt * 128 + c) * 4 + g) * 8 + j;
  b_hi[idx] = h;
  b_lo[idx] = l;
}

// ---- ft = feat @ fc_w via split-bf16 MFMA, LDS-free; fused el/er epilogue
__global__ __launch_bounds__(256) void gemm_ft(
    const float* __restrict__ feat, const unsigned short* __restrict__ b_hi,
    const unsigned short* __restrict__ b_lo, const float* __restrict__ attn_l,
    const float* __restrict__ attn_r, unsigned short* __restrict__ ft16,
    float* __restrict__ el, float* __restrict__ er) {
  const int tid = threadIdx.x;
  const int lane = tid & 63;
  const int wv = tid >> 6;
  const int cl = lane & 15;
  const int g = lane >> 4;
  const int row = blockIdx.x * 64 + wv * 16 + cl;
  const size_t arow = (size_t)min(row, NN - 1) * KIN;
  const int boff0 = cl * 32 + g * 8;

  f32x4 acc[8];
#pragma unroll
  for (int ct = 0; ct < 8; ++ct) acc[ct] = (f32x4){0.f, 0.f, 0.f, 0.f};

#pragma unroll
  for (int kt = 0; kt < 8; ++kt) {
    const float* ap = feat + arow + kt * 32 + g * 8;
    float4 a0 = *(const float4*)ap;
    float4 a1 = *(const float4*)(ap + 4);
    bf16x8 ah, alo;
    {
      float f[8] = {a0.x, a0.y, a0.z, a0.w, a1.x, a1.y, a1.z, a1.w};
#pragma unroll
      for (int j = 0; j < 8; ++j) {
        unsigned short h = f2b(f[j]);
        ah[j] = (short)h;
        alo[j] = (short)f2b(f[j] - b2f(h));
      }
    }
    const unsigned short* bh = b_hi + kt * 4096 + boff0;
    const unsigned short* bl = b_lo + kt * 4096 + boff0;
#pragma unroll
    for (int ct = 0; ct < 8; ++ct) {
      bf16x8 bhv = *(const bf16x8*)(bh + ct * 512);
      bf16x8 blv = *(const bf16x8*)(bl + ct * 512);
      acc[ct] = __builtin_amdgcn_mfma_f32_16x16x32_bf16(ah, bhv, acc[ct], 0, 0, 0);
      acc[ct] = __builtin_amdgcn_mfma_f32_16x16x32_bf16(alo, bhv, acc[ct], 0, 0, 0);
      acc[ct] = __builtin_amdgcn_mfma_f32_16x16x32_bf16(ah, blv, acc[ct], 0, 0, 0);
    }
  }

  float pl[4] = {0, 0, 0, 0}, pr[4] = {0, 0, 0, 0};
  const int r0 = blockIdx.x * 64 + wv * 16 + g * 4;
#pragma unroll
  for (int ct = 0; ct < 8; ++ct) {
    int col = ct * 16 + cl;
    float av = attn_l[col];
    float bv = attn_r[col];
#pragma unroll
    for (int q = 0; q < 4; ++q) {
      float v = acc[ct][q];
      int r = r0 + q;
      if (r < NN) ft16[(size_t)r * DOUT + col] = f2b(v);
      pl[q] = fmaf(v, av, pl[q]);
      pr[q] = fmaf(v, bv, pr[q]);
    }
  }
#pragma unroll
  for (int q = 0; q < 4; ++q) {
    float a = pl[q], b = pr[q];
#pragma unroll
    for (int d = 1; d < 16; d <<= 1) {
      a += __shfl_xor(a, d);
      b += __shfl_xor(b, d);
    }
    if (cl == 0) {
      int r = r0 + q;
      if (r < NN) { el[r] = a; er[r] = b; }
    }
  }
}

// ---- per-block group histogram (LDS atomics only; writes count matrix bin-major)
__global__ __launch_bounds__(256) void k_hist(const int* __restrict__ dst,
                                              int* __restrict__ hist) {
  __shared__ int lh[NG];
  const int tid = threadIdx.x, b = blockIdx.x;
  for (int i = tid; i < NG; i += 256) lh[i] = 0;
  __syncthreads();
  const int base = b * EPB;
#pragma unroll
  for (int it = 0; it < EPB / 1024; ++it) {
    int e = base + it * 1024 + tid * 4;
    if (e < NE) {  // NE%4==0, e%4==0 -> e+3 in range
      int4 d4 = *(const int4*)(dst + e);
      atomicAdd(&lh[d4.x >> GB], 1);
      atomicAdd(&lh[d4.y >> GB], 1);
      atomicAdd(&lh[d4.z >> GB], 1);
      atomicAdd(&lh[d4.w >> GB], 1);
    }
  }
  __syncthreads();
  for (int i = tid; i < NG; i += 256) hist[i * NB + b] = lh[i];
}

// ---- 3-kernel exclusive scan over HTOT ints
__global__ void scan_blk(const int* __restrict__ in, int* __restrict__ out,
                         int* __restrict__ bsums, int n) {
  __shared__ int s[256];
  int tid = threadIdx.x;
  int base = blockIdx.x * 2048 + tid * 8;
  int v[8];
  int tot = 0;
#pragma unroll
  for (int j = 0; j < 8; ++j) {
    int i = base + j;
    v[j] = (i < n) ? in[i] : 0;
    tot += v[j];
  }
  s[tid] = tot;
  __syncthreads();
  for (int d = 1; d < 256; d <<= 1) {
    int t = (tid >= d) ? s[tid - d] : 0;
    __syncthreads();
    s[tid] += t;
    __syncthreads();
  }
  int run = s[tid] - tot;
  if (tid == 255) bsums[blockIdx.x] = s[255];
#pragma unroll
  for (int j = 0; j < 8; ++j) {
    int i = base + j;
    if (i < n) out[i] = run;
    run += v[j];
  }
}

__global__ void scan_tops(int* __restrict__ bsums, int nb) {
  int l = threadIdx.x;
  int v = (l < nb) ? bsums[l] : 0;
  int inc = v;
#pragma unroll
  for (int d = 1; d < 64; d <<= 1) {
    int t = __shfl_up(inc, d);
    if (l >= d) inc += t;
  }
  if (l < nb) bsums[l] = inc - v;
}

__global__ void scan_add2(int* __restrict__ out, const int* __restrict__ bsums, int n) {
  int i = blockIdx.x * 256 + threadIdx.x;
  if (i < n) out[i] += bsums[i >> 11];
}

// ---- scatter into pre-reserved per-(group,block) ranges: NO global atomics
__global__ __launch_bounds__(256) void k_scatter(
    const int* __restrict__ src, const int* __restrict__ dst, const float* __restrict__ w,
    const int* __restrict__ S, uint2* __restrict__ ebuf) {
  __shared__ int cur[NG];
  const int tid = threadIdx.x, b = blockIdx.x;
  for (int i = tid; i < NG; i += 256) cur[i] = S[i * NB + b];
  __syncthreads();
  const int base = b * EPB;
#pragma unroll
  for (int it = 0; it < EPB / 1024; ++it) {
    int e = base + it * 1024 + tid * 4;
    if (e < NE) {
      int4 s4 = *(const int4*)(src + e);
      int4 d4 = *(const int4*)(dst + e);
      float4 w4 = *(const float4*)(w + e);
      int p0 = atomicAdd(&cur[d4.x >> GB], 1);
      ebuf[p0] = make_uint2(((unsigned)s4.x << 16) | f2h(w4.x), (unsigned)d4.x);
      int p1 = atomicAdd(&cur[d4.y >> GB], 1);
      ebuf[p1] = make_uint2(((unsigned)s4.y << 16) | f2h(w4.y), (unsigned)d4.y);
      int p2 = atomicAdd(&cur[d4.z >> GB], 1);
      ebuf[p2] = make_uint2(((unsigned)s4.z << 16) | f2h(w4.z), (unsigned)d4.z);
      int p3 = atomicAdd(&cur[d4.w >> GB], 1);
      ebuf[p3] = make_uint2(((unsigned)s4.w << 16) | f2h(w4.w), (unsigned)d4.w);
    }
  }
}

// ---- fused: LDS counting-sort of group's edges + per-dst softmax + gather-aggregate
__global__ __launch_bounds__(256) void agg(
    const unsigned short* __restrict__ ft16, const uint2* __restrict__ ebuf,
    const int* __restrict__ S, const float* __restrict__ el,
    const float* __restrict__ er, const float* __restrict__ bias,
    float* __restrict__ out) {
  __shared__ uint2 ents[GCAP];
  __shared__ unsigned int sorted[GCAP];
  __shared__ int lh[GSZ], pfx[GSZ], cu[GSZ];
  const int g = blockIdx.x, tid = threadIdx.x;
  const int gbeg = S[g * NB];
  const int gend = (g == NG - 1) ? NE : S[(g + 1) * NB];
  const int cnt = min(gend - gbeg, GCAP);

  if (tid < GSZ) lh[tid] = 0;
  __syncthreads();
  for (int i = tid; i < cnt; i += 256) {
    uint2 en = ebuf[gbeg + i];
    ents[i] = en;
    atomicAdd(&lh[en.y & (GSZ - 1)], 1);
  }
  __syncthreads();
  if (tid < GSZ) {  // wave 0 does the 64-entry exclusive scan
    int v = lh[tid];
    int inc = v;
#pragma unroll
    for (int d = 1; d < 64; d <<= 1) {
      int t = __shfl_up(inc, d);
      if (tid >= d) inc += t;
    }
    pfx[tid] = inc - v;
    cu[tid] = inc - v;
  }
  __syncthreads();
  for (int i = tid; i < cnt; i += 256) {
    uint2 en = ents[i];
    int pos = atomicAdd(&cu[en.y & (GSZ - 1)], 1);
    sorted[pos] = en.x;
  }
  __syncthreads();

  const int lane = tid & 63;
  const int wv = tid >> 6;
  for (int ld = wv; ld < GSZ; ld += 4) {
    int node = g * GSZ + ld;
    if (node >= NN) continue;  // wave-uniform
    int beg = pfx[ld];
    int dg = min(lh[ld], 64);
    float ern = er[node];
    float z = 0.f, zw = 0.f;
    int so = 0;
    if (lane < dg) {
      unsigned u = sorted[beg + lane];
      int s = (int)(u >> 16);
      so = s * DOUT;
      float x = el[s] + ern;
      x = (x > 0.f) ? x : NEG_SLOPE * x;
      z = __expf(x);  // max-free: |logit| bounded ~12
      zw = __expf(h2f((unsigned short)(u & 0xffffu)));
    }
    float se = z, sw = zw;
#pragma unroll
    for (int d = 1; d < 64; d <<= 1) {
      se += __shfl_xor(se, d);
      sw += __shfl_xor(sw, d);
    }
    float coef = z * ((1.f - ALPHA) / se) + zw * (ALPHA / sw);

    float acc[8] = {0.f, 0.f, 0.f, 0.f, 0.f, 0.f, 0.f, 0.f};
    const unsigned short* ftp = ft16 + (lane & 15) * 8;
    for (int jb = 0; jb < dg; jb += 4) {
      int j = jb + (lane >> 4);
      float cj = __shfl(coef, j);  // 0 beyond dg -> harmless row-0 read
      int soj = __shfl(so, j);
      bf16x8 row = *(const bf16x8*)(ftp + soj);
#pragma unroll
      for (int c = 0; c < 8; ++c)
        acc[c] = fmaf(cj, b2f((unsigned short)row[c]), acc[c]);
    }
#pragma unroll
    for (int c = 0; c < 8; ++c) {
      acc[c] += __shfl_xor(acc[c], 16);
      acc[c] += __shfl_xor(acc[c], 32);
    }
    if (lane < 16) {
      const float4 b0 = *(const float4*)(bias + lane * 8);
      const float4 b1 = *(const float4*)(bias + lane * 8 + 4);
      float4 o0, o1;
      o0.x = acc[0] + b0.x; o0.y = acc[1] + b0.y; o0.z = acc[2] + b0.z; o0.w = acc[3] + b0.w;
      o1.x = acc[4] + b1.x; o1.y = acc[5] + b1.y; o1.z = acc[6] + b1.z; o1.w = acc[7] + b1.w;
      float* op = out + (size_t)node * DOUT + lane * 8;
      *(float4*)op = o0;
      *(float4*)(op + 4) = o1;
    }
  }
}

extern "C" void kernel_launch(void* const* d_in, const int* in_sizes, int n_in,
                              void* d_out, int out_size, void* d_ws, size_t ws_size,
                              hipStream_t stream) {
  const float* feat = (const float*)d_in[0];
  const float* w = (const float*)d_in[1];
  const float* fc_w = (const float*)d_in[2];
  const float* attn_l = (const float*)d_in[3];
  const float* attn_r = (const float*)d_in[4];
  const float* bias = (const float*)d_in[5];
  const int* src = (const int*)d_in[6];
  const int* dst = (const int*)d_in[7];
  float* out = (float*)d_out;

  char* ws = (char*)d_ws;
  size_t o = 0;
  auto take = [&](size_t bytes) {
    char* p = ws + o;
    o = (o + bytes + 255) & ~(size_t)255;
    return p;
  };
  unsigned short* ft16 = (unsigned short*)take((size_t)NN * DOUT * 2);
  float* el = (float*)take((size_t)NN * 4);
  float* er = (float*)take((size_t)NN * 4);
  unsigned short* b_hi = (unsigned short*)take((size_t)KIN * DOUT * 2);
  unsigned short* b_lo = (unsigned short*)take((size_t)KIN * DOUT * 2);
  int* hist = (int*)take((size_t)HTOT * 4);
  int* S = (int*)take((size_t)HTOT * 4);
  int* bsums = (int*)take(256);
  uint2* ebuf = (uint2*)take((size_t)NE * 8);

  const int nsb = (HTOT + 2047) / 2048;  // 38
  prep_b<<<(KIN * DOUT + 255) / 256, 256, 0, stream>>>(fc_w, b_hi, b_lo);
  k_hist<<<NB, 256, 0, stream>>>(dst, hist);
  scan_blk<<<nsb, 256, 0, stream>>>(hist, S, bsums, HTOT);
  scan_tops<<<1, 64, 0, stream>>>(bsums, nsb);
  scan_add2<<<(HTOT + 255) / 256, 256, 0, stream>>>(S, bsums, HTOT);
  k_scatter<<<NB, 256, 0, stream>>>(src, dst, w, S, ebuf);
  gemm_ft<<<(NN + 63) / 64, 256, 0, stream>>>(feat, b_hi, b_lo, attn_l, attn_r, ft16, el, er);
  agg<<<NG, 256, 0, stream>>>(ft16, ebuf, S, el, er, bias, out);
}

// Round 7
// 207.023 us; speedup vs baseline: 1.0814x; 1.0666x over previous
//
#include <hip/hip_runtime.h>

#define NN 50000
#define NE 800000
#define KIN 256
#define DOUT 128
#define NEG_SLOPE 0.2f
#define ALPHA 0.5f
#define ELL_CAP 48

#define GEMM_BLKS ((NN + 63) / 64)      // 782
#define FUSED_BLKS (GEMM_BLKS * 5)      // 3910: 1/5 gemm, 4/5 edge

typedef __attribute__((ext_vector_type(8))) short bf16x8;
typedef __attribute__((ext_vector_type(4))) float f32x4;

__device__ __forceinline__ unsigned short f2b(float v) {
  unsigned int u = __float_as_uint(v);
  return (unsigned short)((u + 0x7fffu + ((u >> 16) & 1u)) >> 16);
}
__device__ __forceinline__ float b2f(unsigned short h) {
  return __uint_as_float(((unsigned int)h) << 16);
}
__device__ __forceinline__ unsigned short f2h(float v) {
  _Float16 h = (_Float16)v;
  return __builtin_bit_cast(unsigned short, h);
}
__device__ __forceinline__ float h2f(unsigned short u) {
  return (float)__builtin_bit_cast(_Float16, u);
}

// ---- split fc_w into bf16 hi/lo, fragment-friendly layout
// idx = ((kt*128 + c)*4 + g)*8 + j  for k = kt*32 + g*8 + j
__global__ void prep_b(const float* __restrict__ fc_w, unsigned short* __restrict__ b_hi,
                       unsigned short* __restrict__ b_lo) {
  int t = blockIdx.x * 256 + threadIdx.x;
  if (t >= KIN * DOUT) return;
  int k = t >> 7, c = t & 127;
  float v = fc_w[t];
  unsigned short h = f2b(v);
  unsigned short l = f2b(v - b2f(h));
  int kt = k >> 5, kl = k & 31;
  int g = kl >> 3, j = kl & 7;
  int idx = ((kt * 128 + c) * 4 + g) * 8 + j;
  b_hi[idx] = h;
  b_lo[idx] = l;
}

// ---- FUSED front: gemm blocks co-resident with edge-scatter blocks.
//      Disjoint pipes (MFMA/L2 vs atomic latency) overlap on the same CUs.
__global__ __launch_bounds__(256) void fused_front(
    const float* __restrict__ feat, const unsigned short* __restrict__ b_hi,
    const unsigned short* __restrict__ b_lo, const float* __restrict__ attn_l,
    const float* __restrict__ attn_r, unsigned short* __restrict__ ft16,
    float* __restrict__ el, float* __restrict__ er,
    const int* __restrict__ src, const int* __restrict__ dst,
    const float* __restrict__ w, int* __restrict__ deg,
    unsigned int* __restrict__ ell) {
  const int r = blockIdx.x % 5;
  const int q = blockIdx.x / 5;

  if (r != 4) {
    // ---------------- edge ELL scatter: 1 edge/thread, 1 atomic + 4B store
    int e = (q * 4 + r) * 256 + threadIdx.x;
    if (e < NE) {
      int d = dst[e];
      int p = atomicAdd(&deg[d], 1);
      if (p < ELL_CAP) ell[d * ELL_CAP + p] = ((unsigned)src[e] << 16) | f2h(w[e]);
    }
    return;
  }

  // ---------------- gemm: 64 rows/block, split-bf16 MFMA, LDS-free
  const int tid = threadIdx.x;
  const int lane = tid & 63;
  const int wv = tid >> 6;
  const int cl = lane & 15;
  const int g = lane >> 4;
  const int row = q * 64 + wv * 16 + cl;
  const size_t arow = (size_t)min(row, NN - 1) * KIN;
  const int boff0 = cl * 32 + g * 8;

  f32x4 acc[8];
#pragma unroll
  for (int ct = 0; ct < 8; ++ct) acc[ct] = (f32x4){0.f, 0.f, 0.f, 0.f};

#pragma unroll
  for (int kt = 0; kt < 8; ++kt) {
    const float* ap = feat + arow + kt * 32 + g * 8;
    float4 a0 = *(const float4*)ap;
    float4 a1 = *(const float4*)(ap + 4);
    bf16x8 ah, alo;
    {
      float f[8] = {a0.x, a0.y, a0.z, a0.w, a1.x, a1.y, a1.z, a1.w};
#pragma unroll
      for (int j = 0; j < 8; ++j) {
        unsigned short h = f2b(f[j]);
        ah[j] = (short)h;
        alo[j] = (short)f2b(f[j] - b2f(h));
      }
    }
    const unsigned short* bh = b_hi + kt * 4096 + boff0;
    const unsigned short* bl = b_lo + kt * 4096 + boff0;
#pragma unroll
    for (int ct = 0; ct < 8; ++ct) {
      bf16x8 bhv = *(const bf16x8*)(bh + ct * 512);
      bf16x8 blv = *(const bf16x8*)(bl + ct * 512);
      acc[ct] = __builtin_amdgcn_mfma_f32_16x16x32_bf16(ah, bhv, acc[ct], 0, 0, 0);
      acc[ct] = __builtin_amdgcn_mfma_f32_16x16x32_bf16(alo, bhv, acc[ct], 0, 0, 0);
      acc[ct] = __builtin_amdgcn_mfma_f32_16x16x32_bf16(ah, blv, acc[ct], 0, 0, 0);
    }
  }

  float pl[4] = {0, 0, 0, 0}, pr[4] = {0, 0, 0, 0};
  const int r0 = q * 64 + wv * 16 + g * 4;
#pragma unroll
  for (int ct = 0; ct < 8; ++ct) {
    int col = ct * 16 + cl;
    float av = attn_l[col];
    float bv = attn_r[col];
#pragma unroll
    for (int qq = 0; qq < 4; ++qq) {
      float v = acc[ct][qq];
      int rr = r0 + qq;
      if (rr < NN) ft16[(size_t)rr * DOUT + col] = f2b(v);
      pl[qq] = fmaf(v, av, pl[qq]);
      pr[qq] = fmaf(v, bv, pr[qq]);
    }
  }
#pragma unroll
  for (int qq = 0; qq < 4; ++qq) {
    float a = pl[qq], b = pr[qq];
#pragma unroll
    for (int d = 1; d < 16; d <<= 1) {
      a += __shfl_xor(a, d);
      b += __shfl_xor(b, d);
    }
    if (cl == 0) {
      int rr = r0 + qq;
      if (rr < NN) { el[rr] = a; er[rr] = b; }
    }
  }
}

// ---- aggregation: one wave per dst node; softmax in-register;
//      4x-unrolled row gathers (4 outstanding dwordx4 loads per lane)
__global__ __launch_bounds__(256) void agg(
    const unsigned short* __restrict__ ft16, const unsigned int* __restrict__ ell,
    const int* __restrict__ deg, const float* __restrict__ el,
    const float* __restrict__ er, const float* __restrict__ bias,
    float* __restrict__ out) {
  const int lane = threadIdx.x & 63;
  const int wv = threadIdx.x >> 6;
  const int n = blockIdx.x * 4 + wv;
  if (n >= NN) return;
  const int dg = min(deg[n], ELL_CAP);
  const float ern = er[n];

  float z = 0.f, zw = 0.f;
  int so = 0;
  if (lane < dg) {
    unsigned u = ell[n * ELL_CAP + lane];
    int s = (int)(u >> 16);
    so = s * DOUT;
    float x = el[s] + ern;
    x = (x > 0.f) ? x : NEG_SLOPE * x;
    z = __expf(x);                         // max-free: |logit| bounded ~12
    zw = __expf(h2f((unsigned short)(u & 0xffffu)));
  }
  float se = z, sw = zw;
#pragma unroll
  for (int d = 1; d < 64; d <<= 1) {
    se += __shfl_xor(se, d);
    sw += __shfl_xor(sw, d);
  }
  const float coef = z * ((1.f - ALPHA) / se) + zw * (ALPHA / sw);  // 0 for idle lanes

  float acc[8] = {0.f, 0.f, 0.f, 0.f, 0.f, 0.f, 0.f, 0.f};
  const unsigned short* ftp = ft16 + (lane & 15) * 8;
  const int lg = lane >> 4;
  for (int jb = 0; jb < dg; jb += 16) {  // 16 edges per iter, 4 loads/lane in flight
    int j0 = jb + lg;
    float c0 = __shfl(coef, j0), c1 = __shfl(coef, j0 + 4);
    float c2 = __shfl(coef, j0 + 8), c3 = __shfl(coef, j0 + 12);
    int s0 = __shfl(so, j0), s1 = __shfl(so, j0 + 4);
    int s2 = __shfl(so, j0 + 8), s3 = __shfl(so, j0 + 12);
    bf16x8 r0 = *(const bf16x8*)(ftp + s0);   // coef==0 beyond dg -> row-0 read, harmless
    bf16x8 r1 = *(const bf16x8*)(ftp + s1);
    bf16x8 r2 = *(const bf16x8*)(ftp + s2);
    bf16x8 r3 = *(const bf16x8*)(ftp + s3);
#pragma unroll
    for (int c = 0; c < 8; ++c) {
      acc[c] = fmaf(c0, b2f((unsigned short)r0[c]), acc[c]);
      acc[c] = fmaf(c1, b2f((unsigned short)r1[c]), acc[c]);
      acc[c] = fmaf(c2, b2f((unsigned short)r2[c]), acc[c]);
      acc[c] = fmaf(c3, b2f((unsigned short)r3[c]), acc[c]);
    }
  }
#pragma unroll
  for (int c = 0; c < 8; ++c) {
    acc[c] += __shfl_xor(acc[c], 16);
    acc[c] += __shfl_xor(acc[c], 32);
  }
  if (lane < 16) {
    const float4 b0 = *(const float4*)(bias + lane * 8);
    const float4 b1 = *(const float4*)(bias + lane * 8 + 4);
    float4 o0, o1;
    o0.x = acc[0] + b0.x; o0.y = acc[1] + b0.y; o0.z = acc[2] + b0.z; o0.w = acc[3] + b0.w;
    o1.x = acc[4] + b1.x; o1.y = acc[5] + b1.y; o1.z = acc[6] + b1.z; o1.w = acc[7] + b1.w;
    float* op = out + (size_t)n * DOUT + lane * 8;
    *(float4*)op = o0;
    *(float4*)(op + 4) = o1;
  }
}

extern "C" void kernel_launch(void* const* d_in, const int* in_sizes, int n_in,
                              void* d_out, int out_size, void* d_ws, size_t ws_size,
                              hipStream_t stream) {
  const float* feat = (const float*)d_in[0];
  const float* w = (const float*)d_in[1];
  const float* fc_w = (const float*)d_in[2];
  const float* attn_l = (const float*)d_in[3];
  const float* attn_r = (const float*)d_in[4];
  const float* bias = (const float*)d_in[5];
  const int* src = (const int*)d_in[6];
  const int* dst = (const int*)d_in[7];
  float* out = (float*)d_out;

  char* ws = (char*)d_ws;
  size_t o = 0;
  auto take = [&](size_t bytes) {
    char* p = ws + o;
    o = (o + bytes + 255) & ~(size_t)255;
    return p;
  };
  unsigned short* ft16 = (unsigned short*)take((size_t)NN * DOUT * 2);
  float* el = (float*)take((size_t)NN * 4);
  float* er = (float*)take((size_t)NN * 4);
  unsigned short* b_hi = (unsigned short*)take((size_t)KIN * DOUT * 2);
  unsigned short* b_lo = (unsigned short*)take((size_t)KIN * DOUT * 2);
  int* deg = (int*)take((size_t)NN * 4);
  unsigned int* ell = (unsigned int*)take((size_t)NN * ELL_CAP * 4);

  hipMemsetAsync(deg, 0, (size_t)NN * 4, stream);
  prep_b<<<(KIN * DOUT + 255) / 256, 256, 0, stream>>>(fc_w, b_hi, b_lo);
  fused_front<<<FUSED_BLKS, 256, 0, stream>>>(feat, b_hi, b_lo, attn_l, attn_r, ft16,
                                              el, er, src, dst, w, deg, ell);
  agg<<<(NN + 3) / 4, 256, 0, stream>>>(ft16, ell, deg, el, er, bias, out);
}

// Round 8
// 192.385 us; speedup vs baseline: 1.1637x; 1.0761x over previous
//
#include <hip/hip_runtime.h>

#define NN 50000
#define NE 800000
#define KIN 256
#define DOUT 128
#define NEG_SLOPE 0.2f
#define ALPHA 0.5f
#define ELL_CAP 48

#define RSH 9                       // 512 nodes per region
#define RSZ 512
#define NREG ((NN + RSZ - 1) / RSZ) // 98
#define RCAP 9216                   // mean 8192, sigma ~90 -> 11 sigma headroom
#define EPB 8192                    // edges per pass_a block
#define NAB ((NE + EPB - 1) / EPB)  // 98

#define GEMM_BLKS ((NN + 63) / 64)  // 782

typedef __attribute__((ext_vector_type(8))) short bf16x8;
typedef __attribute__((ext_vector_type(4))) float f32x4;

__device__ __forceinline__ unsigned short f2b(float v) {
  unsigned int u = __float_as_uint(v);
  return (unsigned short)((u + 0x7fffu + ((u >> 16) & 1u)) >> 16);
}
__device__ __forceinline__ float b2f(unsigned short h) {
  return __uint_as_float(((unsigned int)h) << 16);
}
__device__ __forceinline__ unsigned short f2h(float v) {
  _Float16 h = (_Float16)v;
  return __builtin_bit_cast(unsigned short, h);
}
__device__ __forceinline__ float h2f(unsigned short u) {
  return (float)__builtin_bit_cast(_Float16, u);
}

// ---- split fc_w into bf16 hi/lo, fragment-friendly layout
// idx = ((kt*128 + c)*4 + g)*8 + j  for k = kt*32 + g*8 + j
__global__ void prep_b(const float* __restrict__ fc_w, unsigned short* __restrict__ b_hi,
                       unsigned short* __restrict__ b_lo) {
  int t = blockIdx.x * 256 + threadIdx.x;
  if (t >= KIN * DOUT) return;
  int k = t >> 7, c = t & 127;
  float v = fc_w[t];
  unsigned short h = f2b(v);
  unsigned short l = f2b(v - b2f(h));
  int kt = k >> 5, kl = k & 31;
  int g = kl >> 3, j = kl & 7;
  int idx = ((kt * 128 + c) * 4 + g) * 8 + j;
  b_hi[idx] = h;
  b_lo[idx] = l;
}

// ---- pass A: bucket edges by 512-node region; only ~98 global atomics/block
__global__ __launch_bounds__(256) void pass_a(
    const int* __restrict__ src, const int* __restrict__ dst,
    const float* __restrict__ w, int* __restrict__ gcur, uint2* __restrict__ ebuf) {
  __shared__ int hist[NREG];
  __shared__ int cu[NREG];
  const int tid = threadIdx.x, b = blockIdx.x;
  for (int i = tid; i < NREG; i += 256) hist[i] = 0;
  __syncthreads();
  const int base = b * EPB;
#pragma unroll
  for (int it = 0; it < EPB / 1024; ++it) {
    int e = base + it * 1024 + tid * 4;
    if (e < NE) {  // NE%4==0 -> e..e+3 in range
      int4 d4 = *(const int4*)(dst + e);
      atomicAdd(&hist[d4.x >> RSH], 1);
      atomicAdd(&hist[d4.y >> RSH], 1);
      atomicAdd(&hist[d4.z >> RSH], 1);
      atomicAdd(&hist[d4.w >> RSH], 1);
    }
  }
  __syncthreads();
  if (tid < NREG) cu[tid] = atomicAdd(&gcur[tid], hist[tid]);  // within-region offset
  __syncthreads();
#pragma unroll
  for (int it = 0; it < EPB / 1024; ++it) {
    int e = base + it * 1024 + tid * 4;
    if (e < NE) {
      int4 s4 = *(const int4*)(src + e);
      int4 d4 = *(const int4*)(dst + e);
      float4 w4 = *(const float4*)(w + e);
      int r0 = d4.x >> RSH, r1 = d4.y >> RSH, r2 = d4.z >> RSH, r3 = d4.w >> RSH;
      int o0 = atomicAdd(&cu[r0], 1);
      int o1 = atomicAdd(&cu[r1], 1);
      int o2 = atomicAdd(&cu[r2], 1);
      int o3 = atomicAdd(&cu[r3], 1);
      if (o0 < RCAP) ebuf[r0 * RCAP + o0] = make_uint2(((unsigned)s4.x << 16) | f2h(w4.x), d4.x & (RSZ - 1));
      if (o1 < RCAP) ebuf[r1 * RCAP + o1] = make_uint2(((unsigned)s4.y << 16) | f2h(w4.y), d4.y & (RSZ - 1));
      if (o2 < RCAP) ebuf[r2 * RCAP + o2] = make_uint2(((unsigned)s4.z << 16) | f2h(w4.z), d4.z & (RSZ - 1));
      if (o3 < RCAP) ebuf[r3 * RCAP + o3] = make_uint2(((unsigned)s4.w << 16) | f2h(w4.w), d4.w & (RSZ - 1));
    }
  }
}

// ---- fused: pass B (region->ELL, L2-local, zero global atomics) + gemm
__global__ __launch_bounds__(256) void passb_gemm(
    const int* __restrict__ gcur, const uint2* __restrict__ ebuf,
    unsigned int* __restrict__ ell, int* __restrict__ deg,
    const float* __restrict__ feat, const unsigned short* __restrict__ b_hi,
    const unsigned short* __restrict__ b_lo, const float* __restrict__ attn_l,
    const float* __restrict__ attn_r, unsigned short* __restrict__ ft16,
    float* __restrict__ el, float* __restrict__ er) {
  const int tid = threadIdx.x;

  if (blockIdx.x < NREG) {
    // ---------------- pass B: one block per 512-node region
    __shared__ int cnt[RSZ];
    const int r = blockIdx.x;
    for (int i = tid; i < RSZ; i += 256) cnt[i] = 0;
    __syncthreads();
    const int c = min(gcur[r], RCAP);
    const uint2* rb = ebuf + (size_t)r * RCAP;
    for (int i = tid; i < c; i += 256) {
      uint2 en = rb[i];
      int p = atomicAdd(&cnt[en.y], 1);          // LDS atomic
      if (p < ELL_CAP)
        ell[(size_t)((r << RSH) + en.y) * ELL_CAP + p] = en.x;  // L2-local random write
    }
    __syncthreads();
    for (int i = tid; i < RSZ; i += 256) {
      int n = (r << RSH) + i;
      if (n < NN) deg[n] = cnt[i];
    }
    return;
  }

  // ---------------- gemm: 64 rows/block, split-bf16 MFMA, A fully prefetched
  const int q = blockIdx.x - NREG;
  const int lane = tid & 63;
  const int wv = tid >> 6;
  const int cl = lane & 15;
  const int g = lane >> 4;
  const int row = q * 64 + wv * 16 + cl;
  const size_t arow = (size_t)min(row, NN - 1) * KIN;
  const int boff0 = cl * 32 + g * 8;

  float4 abuf[16];
#pragma unroll
  for (int kt = 0; kt < 8; ++kt) {
    const float* ap = feat + arow + kt * 32 + g * 8;
    abuf[2 * kt] = *(const float4*)ap;
    abuf[2 * kt + 1] = *(const float4*)(ap + 4);
  }

  f32x4 acc[8];
#pragma unroll
  for (int ct = 0; ct < 8; ++ct) acc[ct] = (f32x4){0.f, 0.f, 0.f, 0.f};

#pragma unroll
  for (int kt = 0; kt < 8; ++kt) {
    float4 a0 = abuf[2 * kt];
    float4 a1 = abuf[2 * kt + 1];
    bf16x8 ah, alo;
    {
      float f[8] = {a0.x, a0.y, a0.z, a0.w, a1.x, a1.y, a1.z, a1.w};
#pragma unroll
      for (int j = 0; j < 8; ++j) {
        unsigned short h = f2b(f[j]);
        ah[j] = (short)h;
        alo[j] = (short)f2b(f[j] - b2f(h));
      }
    }
    const unsigned short* bh = b_hi + kt * 4096 + boff0;
    const unsigned short* bl = b_lo + kt * 4096 + boff0;
#pragma unroll
    for (int ct = 0; ct < 8; ++ct) {
      bf16x8 bhv = *(const bf16x8*)(bh + ct * 512);
      bf16x8 blv = *(const bf16x8*)(bl + ct * 512);
      acc[ct] = __builtin_amdgcn_mfma_f32_16x16x32_bf16(ah, bhv, acc[ct], 0, 0, 0);
      acc[ct] = __builtin_amdgcn_mfma_f32_16x16x32_bf16(alo, bhv, acc[ct], 0, 0, 0);
      acc[ct] = __builtin_amdgcn_mfma_f32_16x16x32_bf16(ah, blv, acc[ct], 0, 0, 0);
    }
  }

  float pl[4] = {0, 0, 0, 0}, pr[4] = {0, 0, 0, 0};
  const int r0 = q * 64 + wv * 16 + g * 4;
#pragma unroll
  for (int ct = 0; ct < 8; ++ct) {
    int col = ct * 16 + cl;
    float av = attn_l[col];
    float bv = attn_r[col];
#pragma unroll
    for (int qq = 0; qq < 4; ++qq) {
      float v = acc[ct][qq];
      int rr = r0 + qq;
      if (rr < NN) ft16[(size_t)rr * DOUT + col] = f2b(v);
      pl[qq] = fmaf(v, av, pl[qq]);
      pr[qq] = fmaf(v, bv, pr[qq]);
    }
  }
#pragma unroll
  for (int qq = 0; qq < 4; ++qq) {
    float a = pl[qq], b = pr[qq];
#pragma unroll
    for (int d = 1; d < 16; d <<= 1) {
      a += __shfl_xor(a, d);
      b += __shfl_xor(b, d);
    }
    if (cl == 0) {
      int rr = r0 + qq;
      if (rr < NN) { el[rr] = a; er[rr] = b; }
    }
  }
}

// ---- aggregation: one wave per dst node; softmax in-register;
//      4x-unrolled row gathers (4 outstanding dwordx4 loads per lane)
__global__ __launch_bounds__(256) void agg(
    const unsigned short* __restrict__ ft16, const unsigned int* __restrict__ ell,
    const int* __restrict__ deg, const float* __restrict__ el,
    const float* __restrict__ er, const float* __restrict__ bias,
    float* __restrict__ out) {
  const int lane = threadIdx.x & 63;
  const int wv = threadIdx.x >> 6;
  const int n = blockIdx.x * 4 + wv;
  if (n >= NN) return;
  const int dg = min(deg[n], ELL_CAP);
  const float ern = er[n];

  float z = 0.f, zw = 0.f;
  int so = 0;
  if (lane < dg) {
    unsigned u = ell[(size_t)n * ELL_CAP + lane];
    int s = (int)(u >> 16);
    so = s * DOUT;
    float x = el[s] + ern;
    x = (x > 0.f) ? x : NEG_SLOPE * x;
    z = __expf(x);                         // max-free: |logit| bounded ~12
    zw = __expf(h2f((unsigned short)(u & 0xffffu)));
  }
  float se = z, sw = zw;
#pragma unroll
  for (int d = 1; d < 64; d <<= 1) {
    se += __shfl_xor(se, d);
    sw += __shfl_xor(sw, d);
  }
  const float coef = z * ((1.f - ALPHA) / se) + zw * (ALPHA / sw);  // 0 for idle lanes

  float acc[8] = {0.f, 0.f, 0.f, 0.f, 0.f, 0.f, 0.f, 0.f};
  const unsigned short* ftp = ft16 + (lane & 15) * 8;
  const int lg = lane >> 4;
  for (int jb = 0; jb < dg; jb += 16) {  // 16 edges per iter, 4 loads/lane in flight
    int j0 = jb + lg;
    float c0 = __shfl(coef, j0), c1 = __shfl(coef, j0 + 4);
    float c2 = __shfl(coef, j0 + 8), c3 = __shfl(coef, j0 + 12);
    int s0 = __shfl(so, j0), s1 = __shfl(so, j0 + 4);
    int s2 = __shfl(so, j0 + 8), s3 = __shfl(so, j0 + 12);
    bf16x8 r0 = *(const bf16x8*)(ftp + s0);   // coef==0 beyond dg -> row-0 read, harmless
    bf16x8 r1 = *(const bf16x8*)(ftp + s1);
    bf16x8 r2 = *(const bf16x8*)(ftp + s2);
    bf16x8 r3 = *(const bf16x8*)(ftp + s3);
#pragma unroll
    for (int c = 0; c < 8; ++c) {
      acc[c] = fmaf(c0, b2f((unsigned short)r0[c]), acc[c]);
      acc[c] = fmaf(c1, b2f((unsigned short)r1[c]), acc[c]);
      acc[c] = fmaf(c2, b2f((unsigned short)r2[c]), acc[c]);
      acc[c] = fmaf(c3, b2f((unsigned short)r3[c]), acc[c]);
    }
  }
#pragma unroll
  for (int c = 0; c < 8; ++c) {
    acc[c] += __shfl_xor(acc[c], 16);
    acc[c] += __shfl_xor(acc[c], 32);
  }
  if (lane < 16) {
    const float4 b0 = *(const float4*)(bias + lane * 8);
    const float4 b1 = *(const float4*)(bias + lane * 8 + 4);
    float4 o0, o1;
    o0.x = acc[0] + b0.x; o0.y = acc[1] + b0.y; o0.z = acc[2] + b0.z; o0.w = acc[3] + b0.w;
    o1.x = acc[4] + b1.x; o1.y = acc[5] + b1.y; o1.z = acc[6] + b1.z; o1.w = acc[7] + b1.w;
    float* op = out + (size_t)n * DOUT + lane * 8;
    *(float4*)op = o0;
    *(float4*)(op + 4) = o1;
  }
}

extern "C" void kernel_launch(void* const* d_in, const int* in_sizes, int n_in,
                              void* d_out, int out_size, void* d_ws, size_t ws_size,
                              hipStream_t stream) {
  const float* feat = (const float*)d_in[0];
  const float* w = (const float*)d_in[1];
  const float* fc_w = (const float*)d_in[2];
  const float* attn_l = (const float*)d_in[3];
  const float* attn_r = (const float*)d_in[4];
  const float* bias = (const float*)d_in[5];
  const int* src = (const int*)d_in[6];
  const int* dst = (const int*)d_in[7];
  float* out = (float*)d_out;

  char* ws = (char*)d_ws;
  size_t o = 0;
  auto take = [&](size_t bytes) {
    char* p = ws + o;
    o = (o + bytes + 255) & ~(size_t)255;
    return p;
  };
  unsigned short* ft16 = (unsigned short*)take((size_t)NN * DOUT * 2);
  float* el = (float*)take((size_t)NN * 4);
  float* er = (float*)take((size_t)NN * 4);
  unsigned short* b_hi = (unsigned short*)take((size_t)KIN * DOUT * 2);
  unsigned short* b_lo = (unsigned short*)take((size_t)KIN * DOUT * 2);
  int* gcur = (int*)take((size_t)NREG * 4);
  int* deg = (int*)take((size_t)NN * 4);
  uint2* ebuf = (uint2*)take((size_t)NREG * RCAP * 8);
  unsigned int* ell = (unsigned int*)take((size_t)(NREG * RSZ) * ELL_CAP * 4);

  hipMemsetAsync(gcur, 0, (size_t)NREG * 4, stream);
  prep_b<<<(KIN * DOUT + 255) / 256, 256, 0, stream>>>(fc_w, b_hi, b_lo);
  pass_a<<<NAB, 256, 0, stream>>>(src, dst, w, gcur, ebuf);
  passb_gemm<<<NREG + GEMM_BLKS, 256, 0, stream>>>(gcur, ebuf, ell, deg, feat, b_hi, b_lo,
                                                   attn_l, attn_r, ft16, el, er);
  agg<<<(NN + 3) / 4, 256, 0, stream>>>(ft16, ell, deg, el, er, bias, out);
}